// Round 1
// 278.525 us; speedup vs baseline: 1.0174x; 1.0174x over previous
//
#include <hip/hip_runtime.h>
#include <hip/hip_bf16.h>

// B=4, S=512, T=32, D_MODEL=512, N_HEAD=8, D_HEAD=64;  BS=2048.
// Inputs fp32; bf16 MFMA/VALU compute.
//
// Algebraic decomposition (replaces the 68.7 GFLOP kv GEMM + kv round-trip):
//   score[bs,h,t] = (Wk_h^T q_h) . tgt_t   -> qk = batched GEMM (1 GFLOP)
//   o_h = Wv_h . (sum_t p_t tgt_t) + b_v   -> tbar in the same tgt pass
//   b_k cancels (softmax shift-invariance); sum_t p_t = 1 keeps b_v exact.
//
// This revision:
//   - prep: 3x cvt4 + tr_kv merged into ONE kernel (fewer launch gaps)
//   - gemm128: XOR-swizzled LDS (pre-swizzled global source, rule-21) kills
//     the 16-way ds_read_b128 bank conflict of the linear [128][64] layout
//   - fused_attn: lane-staggered iteration order makes both the score read
//     (was 4-way) and tbar read (was 8-way) bank-uniform; reductions commute
#define BS_   2048
#define T_    32
#define DM_   512
#define LDT   520    // LDS row stride (shorts) for 32x512 tgt tile

typedef __attribute__((ext_vector_type(8))) short frag8;   // 8 bf16
typedef __attribute__((ext_vector_type(4))) float f32x4;

__device__ __forceinline__ short f2s(float v) {
    return __builtin_bit_cast(short, __float2bfloat16(v));
}
__device__ __forceinline__ float s2f(short x) {   // bf16 bits -> f32 (1 op)
    return __builtin_bit_cast(float, (unsigned)(unsigned short)x << 16);
}
__device__ __forceinline__ void stv(float* p, float v)          { *p = v; }
__device__ __forceinline__ void stv(__hip_bfloat16* p, float v) { *p = __float2bfloat16(v); }

__device__ __forceinline__ void gl_lds16(const __hip_bfloat16* g, __hip_bfloat16* l) {
    __builtin_amdgcn_global_load_lds(
        (const __attribute__((address_space(1))) unsigned int*)g,
        (__attribute__((address_space(3))) unsigned int*)l, 16, 0, 0);
}

// ---------------- prep: all fp32->bf16 converts + Wkv transpose -------------
// blocks [0,2048): cvt ipw|opw|src (524288 float4 total, 1/thread)
// blocks [2048,2176): 64x64-tiled transpose Tk[c,j] = bf16(ipw[512+j, c])
__global__ __launch_bounds__(256)
void prep(const float* __restrict__ ipw, const float* __restrict__ opw,
          const float* __restrict__ src,
          __hip_bfloat16* __restrict__ ipw_bf, __hip_bfloat16* __restrict__ opw_bf,
          __hip_bfloat16* __restrict__ src_bf, __hip_bfloat16* __restrict__ Tk)
{
    __shared__ __hip_bfloat16 tile[64][65];
    int b = blockIdx.x;
    if (b < 2048) {
        int g = b * 256 + threadIdx.x;     // float4 index
        const float4* in; ushort4* out; int off;
        if (g < 196608)      { in = (const float4*)ipw; out = (ushort4*)ipw_bf; off = g; }
        else if (g < 262144) { in = (const float4*)opw; out = (ushort4*)opw_bf; off = g - 196608; }
        else                 { in = (const float4*)src; out = (ushort4*)src_bf; off = g - 262144; }
        float4 v = in[off];
        ushort4 o;
        o.x = (unsigned short)f2s(v.x); o.y = (unsigned short)f2s(v.y);
        o.z = (unsigned short)f2s(v.z); o.w = (unsigned short)f2s(v.w);
        out[off] = o;
    } else {
        int bb = b - 2048;
        int bx = bb & 15, by = bb >> 4;    // bx: j-tile (16), by: c-tile (8)
        int tid = threadIdx.x;
        const float* sp = ipw + (size_t)512 * 512;
#pragma unroll
        for (int i = 0; i < 16; ++i) {
            int idx = i * 256 + tid;
            int r = idx >> 6, c = idx & 63;
            tile[r][c] = __float2bfloat16(sp[(size_t)(bx * 64 + r) * 512 + by * 64 + c]);
        }
        __syncthreads();
#pragma unroll
        for (int i = 0; i < 16; ++i) {
            int idx = i * 256 + tid;
            int rr = idx >> 6, cc = idx & 63;
            Tk[(size_t)(by * 64 + rr) * 1024 + bx * 64 + cc] = tile[cc][rr];
        }
    }
}

// ---------------- m97-style 128x128 LDS-staged B^T GEMM, XOR-swizzled -------
// LDS layout: sX[row][cb] holds X[row][cb ^ (row&7)] (8-short column blocks).
// global_load_lds dest stays linear (HW requirement); the swizzle is applied
// to the per-lane GLOBAL source address (same 128B segment -> coalescing kept)
// and to the ds_read_b128 address (row&7 == m&7 for all fragment rows).
template<typename OUTT>
__global__ __launch_bounds__(256)
void gemm128(const __hip_bfloat16* __restrict__ A,
             const __hip_bfloat16* __restrict__ W,
             const float* __restrict__ bias,
             OUTT* __restrict__ C,
             const int* __restrict__ zrow,
             int M, int N, int K)
{
    __shared__ __hip_bfloat16 sA[128 * 64];
    __shared__ __hip_bfloat16 sB[128 * 64];

    int tid  = threadIdx.x;
    int lane = tid & 63;
    int wave = tid >> 6;
    int tn = blockIdx.x, tm = blockIdx.y;
    int wm = wave >> 1, wn = wave & 1;

    const __hip_bfloat16* Ab = A + (size_t)tm * 128 * K;
    const __hip_bfloat16* Wb = W + (size_t)tn * 128 * K;

    f32x4 acc[4][4];
#pragma unroll
    for (int i = 0; i < 4; ++i)
#pragma unroll
        for (int j = 0; j < 4; ++j) acc[i][j] = {0.f, 0.f, 0.f, 0.f};

    int wbase = (tid & ~63) * 8;
    int m  = lane & 15;
    int q  = lane >> 4;
    int sw = (m & 7) * 8;                       // read-side XOR (in shorts)
    int trow = tid >> 3;                        // staging row within 32-row chunk
    int tcb  = ((tid & 7) ^ (trow & 7)) * 8;    // pre-swizzled source col-block

    for (int k0 = 0; k0 < K; k0 += 64) {
#pragma unroll
        for (int i = 0; i < 4; ++i)
            gl_lds16(Ab + (size_t)(i * 32 + trow) * K + k0 + tcb, &sA[i * 2048 + wbase]);
#pragma unroll
        for (int i = 0; i < 4; ++i)
            gl_lds16(Wb + (size_t)(i * 32 + trow) * K + k0 + tcb, &sB[i * 2048 + wbase]);
        __syncthreads();
#pragma unroll
        for (int ki = 0; ki < 2; ++ki) {
            frag8 af[4], bf[4];
#pragma unroll
            for (int i = 0; i < 4; ++i)
                af[i] = *(const frag8*)&sA[(wm * 64 + i * 16 + m) * 64 + (((ki * 4 + q) * 8) ^ sw)];
#pragma unroll
            for (int j = 0; j < 4; ++j)
                bf[j] = *(const frag8*)&sB[(wn * 64 + j * 16 + m) * 64 + (((ki * 4 + q) * 8) ^ sw)];
#pragma unroll
            for (int i = 0; i < 4; ++i)
#pragma unroll
                for (int j = 0; j < 4; ++j)
                    acc[i][j] = __builtin_amdgcn_mfma_f32_16x16x32_bf16(
                        af[i], bf[j], acc[i][j], 0, 0, 0);
        }
        __syncthreads();
    }

    int rb = (lane >> 4) * 4;
#pragma unroll
    for (int j = 0; j < 4; ++j) {
        int   col = tn * 128 + wn * 64 + j * 16 + m;
        float bv  = bias[col];
#pragma unroll
        for (int i = 0; i < 4; ++i) {
            int row0 = tm * 128 + wm * 64 + i * 16 + rb;
#pragma unroll
            for (int t = 0; t < 4; ++t) {
                int   row = row0 + t;
                float v   = acc[i][j][t] + bv;
                if (zrow && zrow[row]) v = 0.f;
                stv(&C[(size_t)row * N + col], v);
            }
        }
    }
}

// ---------------- generic z-batched wave-tile B^T GEMM (32x32/wave) ----------
__global__ __launch_bounds__(256)
void gemm_bt_g(const __hip_bfloat16* __restrict__ A, int lda, long astr,
               const __hip_bfloat16* __restrict__ W, int ldw, long wstr,
               const float* __restrict__ bias, int bstr,
               __hip_bfloat16* __restrict__ C, int ldc, long cstr,
               int M, int N, int K)
{
    int z = blockIdx.y;
    A += (size_t)z * astr;  W += (size_t)z * wstr;  C += (size_t)z * cstr;
    int bcol0 = z * bstr;

    int wave = blockIdx.x * 4 + (threadIdx.x >> 6);
    int lane = threadIdx.x & 63;
    int ntn  = N / 32;
    int tm = wave / ntn, tn = wave - tm * ntn;
    if (tm * 32 >= M) return;

    int r  = lane & 15;
    int kq = (lane >> 4) << 3;
    const __hip_bfloat16* Ap = A + (size_t)(tm * 32 + r) * lda + kq;
    const __hip_bfloat16* Wp = W + (size_t)(tn * 32 + r) * ldw + kq;

    f32x4 acc[2][2];
#pragma unroll
    for (int i = 0; i < 2; ++i)
#pragma unroll
        for (int j = 0; j < 2; ++j) acc[i][j] = {0.f, 0.f, 0.f, 0.f};

    for (int k0 = 0; k0 < K; k0 += 32) {
        frag8 a[2], b[2];
#pragma unroll
        for (int i = 0; i < 2; ++i) a[i] = *(const frag8*)(Ap + (size_t)i * 16 * lda + k0);
#pragma unroll
        for (int j = 0; j < 2; ++j) b[j] = *(const frag8*)(Wp + (size_t)j * 16 * ldw + k0);
#pragma unroll
        for (int i = 0; i < 2; ++i)
#pragma unroll
            for (int j = 0; j < 2; ++j)
                acc[i][j] = __builtin_amdgcn_mfma_f32_16x16x32_bf16(a[i], b[j], acc[i][j], 0, 0, 0);
    }

    int rb = (lane >> 4) * 4;
#pragma unroll
    for (int j = 0; j < 2; ++j) {
        int   col = tn * 32 + j * 16 + r;
        float bv  = bias ? bias[bcol0 + col] : 0.f;
#pragma unroll
        for (int i = 0; i < 2; ++i) {
            int row0 = tm * 32 + i * 16 + rb;
#pragma unroll
            for (int t = 0; t < 4; ++t)
                C[(size_t)(row0 + t) * ldc + col] =
                    __float2bfloat16(acc[i][j][t] + bv);
        }
    }
}

// ---------------- fused score + softmax + tbar (single tgt pass) -------------
// One 256-thr block per (b,s). Lane-staggered iteration order makes the LDS
// reads bank-uniform:
//   score: c8' = (c8 + (t>>3)) & 63  -> 4-way conflict eliminated
//   tbar : tt' = (tt + (j>>2)) & 31  -> 8-way conflict eliminated
// (dot/accumulate reductions commute; only fp32 summation order changes)
__global__ __launch_bounds__(256)
void fused_attn(const float* __restrict__ tgt,
                const __hip_bfloat16* __restrict__ qkh,
                const int* __restrict__ mask,
                __hip_bfloat16* __restrict__ tbar,
                int* __restrict__ zrow)
{
    int bs  = blockIdx.x;
    int tid = threadIdx.x;

    __shared__ __hip_bfloat16 sT[32 * LDT];   // ~33.3 KB
    __shared__ __hip_bfloat16 sQK[4096];      // 8 KB
    __shared__ float sP[8][32];
    __shared__ int   sM[32];

    // stage tgt tile fp32 -> bf16 (float4 loads, 8B LDS stores)
    const float* tg = tgt + (size_t)bs * 32 * 512;
#pragma unroll
    for (int i = 0; i < 16; ++i) {
        int idx = i * 256 + tid;          // 4096 float4 units
        int row = idx >> 7, c4 = (idx & 127) * 4;
        float4 v = *(const float4*)(tg + (size_t)row * 512 + c4);
        ushort4 o;
        o.x = (unsigned short)f2s(v.x); o.y = (unsigned short)f2s(v.y);
        o.z = (unsigned short)f2s(v.z); o.w = (unsigned short)f2s(v.w);
        *(ushort4*)&sT[row * LDT + c4] = o;
    }
    // stage qk row (4096 bf16)
    const ushort4* qk4 = (const ushort4*)(qkh + (size_t)bs * 4096);
#pragma unroll
    for (int i = 0; i < 4; ++i) {
        int idx = i * 256 + tid;
        ((ushort4*)sQK)[idx] = qk4[idx];
    }
    if (tid < 32) sM[tid] = mask[bs * 32 + tid];
    __syncthreads();

    bool allm = true;
#pragma unroll
    for (int t = 0; t < 32; ++t) allm = allm && (sM[t] != 0);

    // scores (lane-staggered over c8 for bank uniformity)
    int h = tid >> 5, t = tid & 31;
    const __hip_bfloat16* qrow = sQK + h * 512;
    const __hip_bfloat16* trow = &sT[t * LDT];
    int rot = t >> 3;                  // 0..3
    float s = 0.f;
#pragma unroll
    for (int c8 = 0; c8 < 64; ++c8) {
        int c = (c8 + rot) & 63;
        frag8 a = *(const frag8*)(trow + c * 8);
        frag8 b = *(const frag8*)(qrow + c * 8);
#pragma unroll
        for (int j = 0; j < 8; ++j) s += s2f(a[j]) * s2f(b[j]);
    }
    s *= 0.125f;                       // 1/sqrt(64)
    if (!allm && sM[t]) s = -__builtin_inff();

    float mx = s;
    for (int off = 16; off; off >>= 1) mx = fmaxf(mx, __shfl_xor(mx, off, 32));
    float e = __expf(s - mx);
    float sum = e;
    for (int off = 16; off; off >>= 1) sum += __shfl_xor(sum, off, 32);
    sP[h][t] = e / sum;
    if (tid == 0) zrow[bs] = allm ? 1 : 0;
    __syncthreads();

    // tbar: thread -> (h2, 16-col block), lane-staggered over tt
    int h2 = tid >> 5, j32 = tid & 31, c0 = j32 * 16;
    int rot2 = j32 >> 2;               // 0..7
    float acc[16];
#pragma unroll
    for (int j = 0; j < 16; ++j) acc[j] = 0.f;
#pragma unroll
    for (int tt = 0; tt < 32; ++tt) {
        int tp = (tt + rot2) & 31;
        float p = sP[h2][tp];
        frag8 v1 = *(const frag8*)&sT[tp * LDT + c0];
        frag8 v2 = *(const frag8*)&sT[tp * LDT + c0 + 8];
#pragma unroll
        for (int j = 0; j < 8; ++j) { acc[j] += p * s2f(v1[j]); acc[8 + j] += p * s2f(v2[j]); }
    }
    ushort4 o1, o2, o3, o4;
    o1.x = (unsigned short)f2s(acc[0]);  o1.y = (unsigned short)f2s(acc[1]);
    o1.z = (unsigned short)f2s(acc[2]);  o1.w = (unsigned short)f2s(acc[3]);
    o2.x = (unsigned short)f2s(acc[4]);  o2.y = (unsigned short)f2s(acc[5]);
    o2.z = (unsigned short)f2s(acc[6]);  o2.w = (unsigned short)f2s(acc[7]);
    o3.x = (unsigned short)f2s(acc[8]);  o3.y = (unsigned short)f2s(acc[9]);
    o3.z = (unsigned short)f2s(acc[10]); o3.w = (unsigned short)f2s(acc[11]);
    o4.x = (unsigned short)f2s(acc[12]); o4.y = (unsigned short)f2s(acc[13]);
    o4.z = (unsigned short)f2s(acc[14]); o4.w = (unsigned short)f2s(acc[15]);
    ushort4* dst = (ushort4*)(tbar + (size_t)bs * 4096 + h2 * 512 + c0);
    dst[0] = o1; dst[1] = o2; dst[2] = o3; dst[3] = o4;
}

extern "C" void kernel_launch(void* const* d_in, const int* in_sizes, int n_in,
                              void* d_out, int out_size, void* d_ws, size_t ws_size,
                              hipStream_t stream)
{
    const float* src  = (const float*)d_in[0]; // (2048,512)
    const float* tgt  = (const float*)d_in[1]; // (65536,512)
    const int*   mask = (const int*)d_in[2];   // (2048,32)
    const float* ipw  = (const float*)d_in[3]; // (1536,512)
    const float* ipb  = (const float*)d_in[4]; // (1536,)
    const float* opw  = (const float*)d_in[5]; // (512,512)
    const float* opb  = (const float*)d_in[6]; // (512,)
    float*       out  = (float*)d_out;         // (2048,512)

    // ws (~42 MB): src_bf 2M | ipw_bf 1.5M | opw_bf .5M | q_bf 2M | Tk 1M
    //              | qkh 16M | tbar 16M | ao_bf 2M | zrow 8K
    char* ws = (char*)d_ws;
    __hip_bfloat16* src_bf = (__hip_bfloat16*)(ws);
    __hip_bfloat16* ipw_bf = (__hip_bfloat16*)(ws + ((size_t)2 << 20));
    __hip_bfloat16* opw_bf = (__hip_bfloat16*)(ws + ((size_t)2 << 20) + 1536 * 512 * 2);
    __hip_bfloat16* q_bf   = (__hip_bfloat16*)(ws + ((size_t)4 << 20));
    __hip_bfloat16* Tk     = (__hip_bfloat16*)(ws + ((size_t)6 << 20));
    __hip_bfloat16* qkh    = (__hip_bfloat16*)(ws + ((size_t)8 << 20));
    __hip_bfloat16* tbar   = (__hip_bfloat16*)(ws + ((size_t)24 << 20));
    __hip_bfloat16* ao_bf  = (__hip_bfloat16*)(ws + ((size_t)40 << 20));
    int*            zrow   = (int*)(ws + ((size_t)42 << 20));

    // 0) all converts + Wkv transpose in one kernel
    prep<<<2176, 256, 0, stream>>>(ipw, opw, src, ipw_bf, opw_bf, src_bf, Tk);

    // 1) q = src @ Wq^T + b_q  (2048x512x512) -> bf16
    gemm128<__hip_bfloat16><<<dim3(4, 16), 256, 0, stream>>>(
        src_bf, ipw_bf, ipb, q_bf, nullptr, BS_, DM_, DM_);

    // 2) qk[m, h*512+c] = sum_d q[m,h*64+d] * Wk[h*64+d, c]   (z = head)
    gemm_bt_g<<<dim3(256, 8), 256, 0, stream>>>(
        q_bf, 512, 64,  Tk, 1024, 64,  nullptr, 0,
        qkh, 4096, 512,  BS_, 512, 64);

    // 3) fused score + softmax + tbar (single pass over tgt) + zrow
    fused_attn<<<BS_, 256, 0, stream>>>(tgt, qkh, mask, tbar, zrow);

    // 4) ao[m, h*64+n] = sum_c tbar[m,h,c]*Wv[h*64+n,c] + b_v[h*64+n]
    gemm_bt_g<<<dim3(32, 8), 256, 0, stream>>>(
        tbar, 4096, 512,  ipw_bf + (size_t)1024 * 512, 512, (long)64 * 512,
        ipb + 1024, 64,
        ao_bf, 512, 64,  BS_, 64, 512);

    // 5) out = ao @ Wout^T + b_out, zero all-masked rows (fp32 out)
    gemm128<float><<<dim3(4, 16), 256, 0, stream>>>(
        ao_bf, opw_bf, opb, out, zrow, BS_, DM_, DM_);
}

// Round 3
// 273.712 us; speedup vs baseline: 1.0353x; 1.0176x over previous
//
#include <hip/hip_runtime.h>
#include <hip/hip_bf16.h>

// B=4, S=512, T=32, D_MODEL=512, N_HEAD=8, D_HEAD=64;  BS=2048.
// Inputs fp32; bf16 MFMA/VALU compute.
//
// Algebraic decomposition (replaces the 68.7 GFLOP kv GEMM + kv round-trip):
//   score[bs,h,t] = (Wk_h^T q_h) . tgt_t   -> qk = batched GEMM (1 GFLOP)
//   o_h = Wv_h . (sum_t p_t tgt_t) + b_v   -> tbar in the same tgt pass
//   b_k cancels (softmax shift-invariance); sum_t p_t = 1 keeps b_v exact.
//
// R3: fused_attn on MFMA via the proven D = X.Y^T fragment convention
//   (both operands row-major along K, exactly as gemm_bt_g). No tr_read.
//   score: S[h][t] = qk x T    (contracts c: reads sS  = T row-major)
//   PV:    tbar[h][c] = P x T  (contracts t: reads sTT = T^T, built by an
//          in-LDS lane-staggered transpose pass; stride 32 = bank-even)
//   P carried as bf16 hi+lo (2 chained MFMAs) for the 2e-3 floor.
//   sP overlays dead sQK; output staging overlays dead sS; LDS 74.5KB.
#define BS_   2048
#define T_    32
#define DM_   512

typedef __attribute__((ext_vector_type(8))) short frag8;   // 8 bf16
typedef __attribute__((ext_vector_type(4))) float f32x4;

__device__ __forceinline__ short f2s(float v) {
    return __builtin_bit_cast(short, __float2bfloat16(v));
}
__device__ __forceinline__ float s2f(short x) {   // bf16 bits -> f32 (1 op)
    return __builtin_bit_cast(float, (unsigned)(unsigned short)x << 16);
}
__device__ __forceinline__ void stv(float* p, float v)          { *p = v; }
__device__ __forceinline__ void stv(__hip_bfloat16* p, float v) { *p = __float2bfloat16(v); }

__device__ __forceinline__ void gl_lds16(const __hip_bfloat16* g, __hip_bfloat16* l) {
    __builtin_amdgcn_global_load_lds(
        (const __attribute__((address_space(1))) unsigned int*)g,
        (__attribute__((address_space(3))) unsigned int*)l, 16, 0, 0);
}

// ---------------- prep: all fp32->bf16 converts + Wkv transpose -------------
// blocks [0,2048): cvt ipw|opw|src (524288 float4 total, 1/thread)
// blocks [2048,2176): 64x64-tiled transpose Tk[c,j] = bf16(ipw[512+j, c])
__global__ __launch_bounds__(256)
void prep(const float* __restrict__ ipw, const float* __restrict__ opw,
          const float* __restrict__ src,
          __hip_bfloat16* __restrict__ ipw_bf, __hip_bfloat16* __restrict__ opw_bf,
          __hip_bfloat16* __restrict__ src_bf, __hip_bfloat16* __restrict__ Tk)
{
    __shared__ __hip_bfloat16 tile[64][65];
    int b = blockIdx.x;
    if (b < 2048) {
        int g = b * 256 + threadIdx.x;     // float4 index
        const float4* in; ushort4* out; int off;
        if (g < 196608)      { in = (const float4*)ipw; out = (ushort4*)ipw_bf; off = g; }
        else if (g < 262144) { in = (const float4*)opw; out = (ushort4*)opw_bf; off = g - 196608; }
        else                 { in = (const float4*)src; out = (ushort4*)src_bf; off = g - 262144; }
        float4 v = in[off];
        ushort4 o;
        o.x = (unsigned short)f2s(v.x); o.y = (unsigned short)f2s(v.y);
        o.z = (unsigned short)f2s(v.z); o.w = (unsigned short)f2s(v.w);
        out[off] = o;
    } else {
        int bb = b - 2048;
        int bx = bb & 15, by = bb >> 4;    // bx: j-tile (16), by: c-tile (8)
        int tid = threadIdx.x;
        const float* sp = ipw + (size_t)512 * 512;
#pragma unroll
        for (int i = 0; i < 16; ++i) {
            int idx = i * 256 + tid;
            int r = idx >> 6, c = idx & 63;
            tile[r][c] = __float2bfloat16(sp[(size_t)(bx * 64 + r) * 512 + by * 64 + c]);
        }
        __syncthreads();
#pragma unroll
        for (int i = 0; i < 16; ++i) {
            int idx = i * 256 + tid;
            int rr = idx >> 6, cc = idx & 63;
            Tk[(size_t)(by * 64 + rr) * 1024 + bx * 64 + cc] = tile[cc][rr];
        }
    }
}

// ---------------- m97-style 128x128 LDS-staged B^T GEMM, XOR-swizzled -------
template<typename OUTT>
__global__ __launch_bounds__(256)
void gemm128(const __hip_bfloat16* __restrict__ A,
             const __hip_bfloat16* __restrict__ W,
             const float* __restrict__ bias,
             OUTT* __restrict__ C,
             const int* __restrict__ zrow,
             int M, int N, int K)
{
    __shared__ __hip_bfloat16 sA[128 * 64];
    __shared__ __hip_bfloat16 sB[128 * 64];

    int tid  = threadIdx.x;
    int lane = tid & 63;
    int wave = tid >> 6;
    int tn = blockIdx.x, tm = blockIdx.y;
    int wm = wave >> 1, wn = wave & 1;

    const __hip_bfloat16* Ab = A + (size_t)tm * 128 * K;
    const __hip_bfloat16* Wb = W + (size_t)tn * 128 * K;

    f32x4 acc[4][4];
#pragma unroll
    for (int i = 0; i < 4; ++i)
#pragma unroll
        for (int j = 0; j < 4; ++j) acc[i][j] = {0.f, 0.f, 0.f, 0.f};

    int wbase = (tid & ~63) * 8;
    int m  = lane & 15;
    int q  = lane >> 4;
    int sw = (m & 7) * 8;                       // read-side XOR (in shorts)
    int trow = tid >> 3;                        // staging row within 32-row chunk
    int tcb  = ((tid & 7) ^ (trow & 7)) * 8;    // pre-swizzled source col-block

    for (int k0 = 0; k0 < K; k0 += 64) {
#pragma unroll
        for (int i = 0; i < 4; ++i)
            gl_lds16(Ab + (size_t)(i * 32 + trow) * K + k0 + tcb, &sA[i * 2048 + wbase]);
#pragma unroll
        for (int i = 0; i < 4; ++i)
            gl_lds16(Wb + (size_t)(i * 32 + trow) * K + k0 + tcb, &sB[i * 2048 + wbase]);
        __syncthreads();
#pragma unroll
        for (int ki = 0; ki < 2; ++ki) {
            frag8 af[4], bf[4];
#pragma unroll
            for (int i = 0; i < 4; ++i)
                af[i] = *(const frag8*)&sA[(wm * 64 + i * 16 + m) * 64 + (((ki * 4 + q) * 8) ^ sw)];
#pragma unroll
            for (int j = 0; j < 4; ++j)
                bf[j] = *(const frag8*)&sB[(wn * 64 + j * 16 + m) * 64 + (((ki * 4 + q) * 8) ^ sw)];
#pragma unroll
            for (int i = 0; i < 4; ++i)
#pragma unroll
                for (int j = 0; j < 4; ++j)
                    acc[i][j] = __builtin_amdgcn_mfma_f32_16x16x32_bf16(
                        af[i], bf[j], acc[i][j], 0, 0, 0);
        }
        __syncthreads();
    }

    int rb = (lane >> 4) * 4;
#pragma unroll
    for (int j = 0; j < 4; ++j) {
        int   col = tn * 128 + wn * 64 + j * 16 + m;
        float bv  = bias[col];
#pragma unroll
        for (int i = 0; i < 4; ++i) {
            int row0 = tm * 128 + wm * 64 + i * 16 + rb;
#pragma unroll
            for (int t = 0; t < 4; ++t) {
                int   row = row0 + t;
                float v   = acc[i][j][t] + bv;
                if (zrow && zrow[row]) v = 0.f;
                stv(&C[(size_t)row * N + col], v);
            }
        }
    }
}

// ---------------- generic z-batched wave-tile B^T GEMM (32x32/wave) ----------
__global__ __launch_bounds__(256)
void gemm_bt_g(const __hip_bfloat16* __restrict__ A, int lda, long astr,
               const __hip_bfloat16* __restrict__ W, int ldw, long wstr,
               const float* __restrict__ bias, int bstr,
               __hip_bfloat16* __restrict__ C, int ldc, long cstr,
               int M, int N, int K)
{
    int z = blockIdx.y;
    A += (size_t)z * astr;  W += (size_t)z * wstr;  C += (size_t)z * cstr;
    int bcol0 = z * bstr;

    int wave = blockIdx.x * 4 + (threadIdx.x >> 6);
    int lane = threadIdx.x & 63;
    int ntn  = N / 32;
    int tm = wave / ntn, tn = wave - tm * ntn;
    if (tm * 32 >= M) return;

    int r  = lane & 15;
    int kq = (lane >> 4) << 3;
    const __hip_bfloat16* Ap = A + (size_t)(tm * 32 + r) * lda + kq;
    const __hip_bfloat16* Wp = W + (size_t)(tn * 32 + r) * ldw + kq;

    f32x4 acc[2][2];
#pragma unroll
    for (int i = 0; i < 2; ++i)
#pragma unroll
        for (int j = 0; j < 2; ++j) acc[i][j] = {0.f, 0.f, 0.f, 0.f};

    for (int k0 = 0; k0 < K; k0 += 32) {
        frag8 a[2], b[2];
#pragma unroll
        for (int i = 0; i < 2; ++i) a[i] = *(const frag8*)(Ap + (size_t)i * 16 * lda + k0);
#pragma unroll
        for (int j = 0; j < 2; ++j) b[j] = *(const frag8*)(Wp + (size_t)j * 16 * ldw + k0);
#pragma unroll
        for (int i = 0; i < 2; ++i)
#pragma unroll
            for (int j = 0; j < 2; ++j)
                acc[i][j] = __builtin_amdgcn_mfma_f32_16x16x32_bf16(a[i], b[j], acc[i][j], 0, 0, 0);
    }

    int rb = (lane >> 4) * 4;
#pragma unroll
    for (int j = 0; j < 2; ++j) {
        int   col = tn * 32 + j * 16 + r;
        float bv  = bias ? bias[bcol0 + col] : 0.f;
#pragma unroll
        for (int i = 0; i < 2; ++i) {
            int row0 = tm * 32 + i * 16 + rb;
#pragma unroll
            for (int t = 0; t < 4; ++t)
                C[(size_t)(row0 + t) * ldc + col] =
                    __float2bfloat16(acc[i][j][t] + bv);
        }
    }
}

// ---------------- fused score + softmax + tbar, MFMA (no tr_read) -----------
// One 256-thr block per (b,s). All MFMAs use the proven D = X.Y^T convention:
// A-frag lane l = X[row l&15][k-slice (l>>4)*8+j], B-frag lane l = Y[row l&15]
// [same k-slice], D lane l reg r = D[(l>>4)*4+r][l&15]  (gemm_bt_g-verified).
//   score: X = qk rows (dup h&7), Y = T rows   -> S[h][t], t = lane&15 (+16)
//   PV:    X = P rows (hi+lo bf16), Y = T^T rows -> tbar[h][c], c = cg*16+m
__global__ __launch_bounds__(256)
void fused_attn(const float* __restrict__ tgt,
                const __hip_bfloat16* __restrict__ qkh,
                const int* __restrict__ mask,
                __hip_bfloat16* __restrict__ tbar,
                int* __restrict__ zrow)
{
    int bs   = blockIdx.x;
    int tid  = threadIdx.x;
    int lane = tid & 63;
    int wv   = tid >> 6;
    int m    = lane & 15;
    int g4   = lane >> 4;

    __shared__ short sS[32 * 520];    // T row-major (33,280B); reused as sO (8x512)
    __shared__ short sTT[512 * 32];   // T^T row-major (32,768B)
    __shared__ short sQK[8 * 520];    // qk rows (8,320B); reused as sP (4x512)
    __shared__ int   sM[32];

    // ---- stage tgt fp32 -> bf16, row-major ----
    const float* tg = tgt + (size_t)bs * 32 * 512;
#pragma unroll
    for (int i = 0; i < 16; ++i) {
        int idx = i * 256 + tid;          // 4096 float4 units
        int row = idx >> 7, c4 = (idx & 127) * 4;
        float4 v = *(const float4*)(tg + (size_t)row * 512 + c4);
        ushort4 o;
        o.x = (unsigned short)f2s(v.x); o.y = (unsigned short)f2s(v.y);
        o.z = (unsigned short)f2s(v.z); o.w = (unsigned short)f2s(v.w);
        *(ushort4*)&sS[row * 520 + c4] = o;
    }
    // ---- stage qk (8 x 512 bf16) ----
    const ushort4* qk4 = (const ushort4*)(qkh + (size_t)bs * 4096);
#pragma unroll
    for (int i = 0; i < 4; ++i) {
        int u = i * 256 + tid;
        int h = u >> 7, c4 = (u & 127) * 4;
        *(ushort4*)&sQK[h * 520 + c4] = qk4[u];
    }
    if (tid < 32) sM[tid] = mask[bs * 32 + tid];
    __syncthreads();

    // ---- transpose: sTT[c][t] = sS[t][c], lane-staggered (bank-even) ----
    {
        int rot = (tid >> 1) & 7;
#pragma unroll
        for (int cc = 0; cc < 2; ++cc) {
            int c = tid + cc * 256;
#pragma unroll
            for (int s = 0; s < 8; ++s) {
                int t0 = ((s + rot) & 7) * 4;
                ushort4 o;
                o.x = (unsigned short)sS[(t0 + 0) * 520 + c];
                o.y = (unsigned short)sS[(t0 + 1) * 520 + c];
                o.z = (unsigned short)sS[(t0 + 2) * 520 + c];
                o.w = (unsigned short)sS[(t0 + 3) * 520 + c];
                *(ushort4*)&sTT[c * 32 + t0] = o;
            }
        }
    }

    int mk0 = sM[m], mk1 = sM[16 + m];        // masks for t = m, 16+m
    bool allm = __all((mk0 != 0) && (mk1 != 0));
    if (tid == 0) zrow[bs] = allm ? 1 : 0;

    // ---- score: every wave computes full 16x32 S redundantly ----
    f32x4 acc0 = {0.f,0.f,0.f,0.f}, acc1 = {0.f,0.f,0.f,0.f};
    {
        const short* qb  = &sQK[(m & 7) * 520 + g4 * 8];
        const short* t0p = &sS[m * 520 + g4 * 8];
        const short* t1p = t0p + 16 * 520;
#pragma unroll
        for (int k0 = 0; k0 < 512; k0 += 32) {
            frag8 af = *(const frag8*)(qb + k0);
            frag8 b0 = *(const frag8*)(t0p + k0);
            frag8 b1 = *(const frag8*)(t1p + k0);
            acc0 = __builtin_amdgcn_mfma_f32_16x16x32_bf16(af, b0, acc0, 0, 0, 0);
            acc1 = __builtin_amdgcn_mfma_f32_16x16x32_bf16(af, b1, acc1, 0, 0, 0);
        }
    }

    // ---- softmax over t per row h = g4*4+r (16-lane shfl reduce) ----
    float p0v[4], p1v[4];
#pragma unroll
    for (int r = 0; r < 4; ++r) {
        float s0 = acc0[r] * 0.125f, s1 = acc1[r] * 0.125f;
        if (!allm) {
            if (mk0) s0 = -__builtin_inff();
            if (mk1) s1 = -__builtin_inff();
        }
        float mx = fmaxf(s0, s1);
#pragma unroll
        for (int off = 1; off < 16; off <<= 1) mx = fmaxf(mx, __shfl_xor(mx, off));
        float e0 = __expf(s0 - mx), e1 = __expf(s1 - mx);
        float sm = e0 + e1;
#pragma unroll
        for (int off = 1; off < 16; off <<= 1) sm += __shfl_xor(sm, off);
        float inv = 1.f / sm;
        p0v[r] = e0 * inv; p1v[r] = e1 * inv;
    }

    __syncthreads();   // all score reads of sQK done -> safe to overlay sP

    // ---- P (bf16 hi+lo) into sP = sQK overlay, per wave ----
    short* sPw = &sQK[0] + wv * 512;   // 256 hi + 256 lo
    if (g4 < 2) {
#pragma unroll
        for (int r = 0; r < 4; ++r) {
            int h = g4 * 4 + r;
            short h0 = f2s(p0v[r]);
            short h1 = f2s(p1v[r]);
            sPw[h * 32 + m]            = h0;
            sPw[h * 32 + 16 + m]       = h1;
            sPw[256 + h * 32 + m]      = f2s(p0v[r] - s2f(h0));
            sPw[256 + h * 32 + 16 + m] = f2s(p1v[r] - s2f(h1));
        }
    }
    __syncthreads();   // sP visible (conservative)

    frag8 paH = *(const frag8*)(sPw + (m & 7) * 32 + g4 * 8);
    frag8 paL = *(const frag8*)(sPw + 256 + (m & 7) * 32 + g4 * 8);

    // ---- PV: tbar[h][c] = (paH+paL) x T, K=32 in one chained pair ----
    short* sO = &sS[0];               // 8x512 output staging (sS is dead)
#pragma unroll
    for (int ci = 0; ci < 8; ++ci) {
        int cg = wv * 8 + ci;
        frag8 vb = *(const frag8*)(&sTT[(cg * 16 + m) * 32 + g4 * 8]);
        f32x4 d = {0.f,0.f,0.f,0.f};
        d = __builtin_amdgcn_mfma_f32_16x16x32_bf16(paH, vb, d, 0, 0, 0);
        d = __builtin_amdgcn_mfma_f32_16x16x32_bf16(paL, vb, d, 0, 0, 0);
        if (g4 < 2) {
#pragma unroll
            for (int r = 0; r < 4; ++r)
                sO[(g4 * 4 + r) * 512 + cg * 16 + m] = f2s(d[r]);
        }
    }
    __syncthreads();

    // ---- coalesced copy-out (8x512 bf16 = 1024 ushort4) ----
    ushort4* dst = (ushort4*)(tbar + (size_t)bs * 4096);
    const ushort4* so4 = (const ushort4*)sO;
#pragma unroll
    for (int i = 0; i < 4; ++i)
        dst[i * 256 + tid] = so4[i * 256 + tid];
}

extern "C" void kernel_launch(void* const* d_in, const int* in_sizes, int n_in,
                              void* d_out, int out_size, void* d_ws, size_t ws_size,
                              hipStream_t stream)
{
    const float* src  = (const float*)d_in[0]; // (2048,512)
    const float* tgt  = (const float*)d_in[1]; // (65536,512)
    const int*   mask = (const int*)d_in[2];   // (2048,32)
    const float* ipw  = (const float*)d_in[3]; // (1536,512)
    const float* ipb  = (const float*)d_in[4]; // (1536,)
    const float* opw  = (const float*)d_in[5]; // (512,512)
    const float* opb  = (const float*)d_in[6]; // (512,)
    float*       out  = (float*)d_out;         // (2048,512)

    // ws (~42 MB): src_bf 2M | ipw_bf 1.5M | opw_bf .5M | q_bf 2M | Tk 1M
    //              | qkh 16M | tbar 16M | ao_bf 2M | zrow 8K
    char* ws = (char*)d_ws;
    __hip_bfloat16* src_bf = (__hip_bfloat16*)(ws);
    __hip_bfloat16* ipw_bf = (__hip_bfloat16*)(ws + ((size_t)2 << 20));
    __hip_bfloat16* opw_bf = (__hip_bfloat16*)(ws + ((size_t)2 << 20) + 1536 * 512 * 2);
    __hip_bfloat16* q_bf   = (__hip_bfloat16*)(ws + ((size_t)4 << 20));
    __hip_bfloat16* Tk     = (__hip_bfloat16*)(ws + ((size_t)6 << 20));
    __hip_bfloat16* qkh    = (__hip_bfloat16*)(ws + ((size_t)8 << 20));
    __hip_bfloat16* tbar   = (__hip_bfloat16*)(ws + ((size_t)24 << 20));
    __hip_bfloat16* ao_bf  = (__hip_bfloat16*)(ws + ((size_t)40 << 20));
    int*            zrow   = (int*)(ws + ((size_t)42 << 20));

    // 0) all converts + Wkv transpose in one kernel
    prep<<<2176, 256, 0, stream>>>(ipw, opw, src, ipw_bf, opw_bf, src_bf, Tk);

    // 1) q = src @ Wq^T + b_q  (2048x512x512) -> bf16
    gemm128<__hip_bfloat16><<<dim3(4, 16), 256, 0, stream>>>(
        src_bf, ipw_bf, ipb, q_bf, nullptr, BS_, DM_, DM_);

    // 2) qk[m, h*512+c] = sum_d q[m,h*64+d] * Wk[h*64+d, c]   (z = head)
    gemm_bt_g<<<dim3(256, 8), 256, 0, stream>>>(
        q_bf, 512, 64,  Tk, 1024, 64,  nullptr, 0,
        qkh, 4096, 512,  BS_, 512, 64);

    // 3) fused score + softmax + tbar (single pass over tgt) + zrow
    fused_attn<<<BS_, 256, 0, stream>>>(tgt, qkh, mask, tbar, zrow);

    // 4) ao[m, h*64+n] = sum_c tbar[m,h,c]*Wv[h*64+n,c] + b_v[h*64+n]
    gemm_bt_g<<<dim3(32, 8), 256, 0, stream>>>(
        tbar, 4096, 512,  ipw_bf + (size_t)1024 * 512, 512, (long)64 * 512,
        ipb + 1024, 64,
        ao_bf, 512, 64,  BS_, 64, 512);

    // 5) out = ao @ Wout^T + b_out, zero all-masked rows (fp32 out)
    gemm128<float><<<dim3(4, 16), 256, 0, stream>>>(
        ao_bf, opw_bf, opb, out, zrow, BS_, DM_, DM_);
}